// Round 5
// baseline (194.280 us; speedup 1.0000x reference)
//
#include <hip/hip_runtime.h>
#include <math.h>

#define NATOMS 5
#define NEXP 18
#define NBEAD 4
#define EPSV 1e-8f
#define ML2 (0.02f * 0.02f)

// Pack per (expert,bead): 8 triplets, one 16-bit entry each in an int4.
// entry: oi | oj<<4 | ok<<8 | okflag<<12, offsets premultiplied by 3.
__global__ void pack_tables(const int* __restrict__ trip, const int* __restrict__ valid,
                            int4* __restrict__ ptbl) {
    int c = blockIdx.x * blockDim.x + threadIdx.x;
    if (c < NEXP * NBEAD) {
        unsigned w[4] = {0u, 0u, 0u, 0u};
#pragma unroll
        for (int t = 0; t < 8; t++) {
            int b = c * 8 + t;
            int i = trip[b * 3 + 0], j = trip[b * 3 + 1], k = trip[b * 3 + 2];
            unsigned ok = (i >= 0 && j >= 0 && k >= 0 && valid[b] > 0) ? 1u : 0u;
            unsigned oi = 3u * (unsigned)min(max(i, 0), NATOMS - 1);
            unsigned oj = 3u * (unsigned)min(max(j, 0), NATOMS - 1);
            unsigned ov = 3u * (unsigned)min(max(k, 0), NATOMS - 1);
            unsigned e = oi | (oj << 4) | (ov << 8) | (ok << 12);
            w[t >> 1] |= e << ((t & 1) * 16);
        }
        ptbl[c] = make_int4((int)w[0], (int)w[1], (int)w[2], (int)w[3]);
    }
}

// Barrier-free main kernel: one thread per row, direct global loads, LDS used
// only as THREAD-PRIVATE scratch for dynamic triplet gathers. No cross-thread
// dependency until the final block reduction. LDS = 256*32*4 = 32768 B
// (red[] aliases scratch behind the end-of-kernel barrier) -> 5 blocks/CU.
__global__ __launch_bounds__(256, 5) void loss_kernel(
    const float* __restrict__ xin, const float* __restrict__ y_true,
    const float* __restrict__ y_pred, const float* __restrict__ mask,
    const int4* __restrict__ ptbl, float* __restrict__ partial, int n) {
    __shared__ float scr[8192];  // 256 threads x 32 dwords (T at [0,15), P at [16,31))

    const int tid = threadIdx.x;
    const int row = blockIdx.x * 256 + tid;
    float* st = scr + (tid << 5);  // 128B-aligned slice -> b128 LDS writes

    float result = 0.0f;
    if (row < n) {
        const size_t rb = (size_t)row * 15;
        const float* gT = y_true + rb;
        const float* gP = y_pred + rb;
        const float* gM = mask + rb;

        // Independent direct loads (merged to dwordx4/x3 by the vectorizer).
        float T[15], P[15], M[15];
#pragma unroll
        for (int c = 0; c < 15; c++) T[c] = gT[c];
#pragma unroll
        for (int c = 0; c < 15; c++) P[c] = gP[c];
#pragma unroll
        for (int c = 0; c < 15; c++) M[c] = gM[c];

        // Gate/bead load + table fetch (L1-resident), overlaps the row loads.
        float2 gb = *(const float2*)(xin + (size_t)row * 38 + 36);
        float beadf = isfinite(gb.x) ? gb.x : 0.f;
        float gatef = isfinite(gb.y) ? gb.y : 0.f;
        gatef = fminf(fmaxf(gatef, -1e6f), 1e6f);
        beadf = fminf(fmaxf(beadf, -1e6f), 1e6f);
        int res_id = min(max((int)rintf(gatef) - 1, 0), NEXP - 1);
        int bead_id = min(max((int)rintf(beadf), 0), NBEAD - 1);
        int4 pk = ptbl[res_id * NBEAD + bead_id];
        unsigned tw0 = (unsigned)pk.x, tw1 = (unsigned)pk.y;
        unsigned tw2 = (unsigned)pk.z, tw3 = (unsigned)pk.w;

        // Spill own row to private LDS slice (merged ds_write_b128).
#pragma unroll
        for (int c = 0; c < 15; c++) st[c] = T[c];
#pragma unroll
        for (int c = 0; c < 15; c++) st[16 + c] = P[c];

        // ---- atom MSE (mask binary -> exact bit logic) ----
        float num_a = 0.f, den_a = 0.f;
        unsigned avm2 = 0u;  // validity bit at premultiplied offset 3*a
#pragma unroll
        for (int a = 0; a < 5; a++) {
            bool m0 = M[3 * a + 0] > 0.f;
            bool m1 = M[3 * a + 1] > 0.f;
            bool m2 = M[3 * a + 2] > 0.f;
            float d0 = T[3 * a + 0] - P[3 * a + 0];
            float d1 = T[3 * a + 1] - P[3 * a + 1];
            float d2 = T[3 * a + 2] - P[3 * a + 2];
            float se = (m0 ? d0 * d0 : 0.f) + (m1 ? d1 * d1 : 0.f) + (m2 ? d2 * d2 : 0.f);
            if (m0 || m1 || m2) { num_a += se; den_a += 1.f; avm2 |= 1u << (3 * a); }
        }
        result = num_a / (den_a + EPSV);

        // ---- angle part: dynamic gathers from OWN LDS slice ----
        float num_g = 0.f, den_g = 0.f;
#pragma unroll
        for (int t = 0; t < 8; t++) {
            unsigned wrd = (t < 2) ? tw0 : (t < 4) ? tw1 : (t < 6) ? tw2 : tw3;
            unsigned e = (wrd >> ((t & 1) * 16)) & 0xffffu;
            int oi = e & 15, oj = (e >> 4) & 15, ov = (e >> 8) & 15;
            bool wok = ((e >> 12) & 1u) != 0u;

            float tix = st[oi], tiy = st[oi + 1], tiz = st[oi + 2];
            float tjx = st[oj], tjy = st[oj + 1], tjz = st[oj + 2];
            float tkx = st[ov], tky = st[ov + 1], tkz = st[ov + 2];
            float pix = st[16 + oi], piy = st[17 + oi], piz = st[18 + oi];
            float pjx = st[16 + oj], pjy = st[17 + oj], pjz = st[18 + oj];
            float pkx = st[16 + ov], pky = st[17 + ov], pkz = st[18 + ov];

            float v1tx = tix - tjx, v1ty = tiy - tjy, v1tz = tiz - tjz;
            float v2tx = tkx - tjx, v2ty = tky - tjy, v2tz = tkz - tjz;
            float v1px = pix - pjx, v1py = piy - pjy, v1pz = piz - pjz;
            float v2px = pkx - pjx, v2py = pky - pjy, v2pz = pkz - pjz;

            float l1t = fmaf(v1tx, v1tx, fmaf(v1ty, v1ty, v1tz * v1tz));
            float l2t = fmaf(v2tx, v2tx, fmaf(v2ty, v2ty, v2tz * v2tz));
            float l1p = fmaf(v1px, v1px, fmaf(v1py, v1py, v1pz * v1pz));
            float l2p = fmaf(v2px, v2px, fmaf(v2py, v2py, v2pz * v2pz));

            bool okv = wok && ((avm2 >> oi) & 1) && ((avm2 >> oj) & 1) &&
                       ((avm2 >> ov) & 1) && (l1t > ML2) && (l2t > ML2) &&
                       (l1p > ML2) && (l2p > ML2);

            float rt = __builtin_amdgcn_rsqf(fmaxf(l1t, ML2) * fmaxf(l2t, ML2));
            float rp = __builtin_amdgcn_rsqf(fmaxf(l1p, ML2) * fmaxf(l2p, ML2));

            float dott = fmaf(v1tx, v2tx, fmaf(v1ty, v2ty, v1tz * v2tz));
            float dotp = fmaf(v1px, v2px, fmaf(v1py, v2py, v1pz * v2pz));
            float cut = dott * rt;
            float cup = dotp * rp;
            float cost = fminf(fmaxf(cut, -1.f + 1e-6f), 1.f - 1e-6f);
            float cosp = fminf(fmaxf(cup, -1.f + 1e-6f), 1.f - 1e-6f);
            float sint = __builtin_amdgcn_sqrtf(fmaxf(fmaf(-cut, cut, 1.f), 0.f));
            float sinp = __builtin_amdgcn_sqrtf(fmaxf(fmaf(-cup, cup, 1.f), 0.f));

            float dc = cosp - cost, dsn = sinp - sint;
            if (okv) { num_g += fmaf(dc, dc, dsn * dsn); den_g += 1.f; }
        }
        result += num_g / (den_g + EPSV);
    }

    // ---- block reduction (only barrier in the kernel) ----
#pragma unroll
    for (int off = 32; off > 0; off >>= 1)
        result += __shfl_down(result, off, 64);
    __syncthreads();  // protect scratch reuse as red[]
    float* red = scr;
    int lane = tid & 63, wv = tid >> 6;
    if (lane == 0) red[wv] = result;
    __syncthreads();
    if (tid == 0) partial[blockIdx.x] = red[0] + red[1] + red[2] + red[3];
}

__global__ __launch_bounds__(256) void reduce_kernel(const float* __restrict__ partial,
                                                     float* __restrict__ out, int nblocks,
                                                     float inv_n) {
    __shared__ float red[4];
    float s = 0.f;
    for (int i = threadIdx.x; i < nblocks; i += 256) s += partial[i];
#pragma unroll
    for (int off = 32; off > 0; off >>= 1) s += __shfl_down(s, off, 64);
    int lane = threadIdx.x & 63, wv = threadIdx.x >> 6;
    if (lane == 0) red[wv] = s;
    __syncthreads();
    if (threadIdx.x == 0) out[0] = (red[0] + red[1] + red[2] + red[3]) * inv_n;
}

extern "C" void kernel_launch(void* const* d_in, const int* in_sizes, int n_in,
                              void* d_out, int out_size, void* d_ws, size_t ws_size,
                              hipStream_t stream) {
    const float* x = (const float*)d_in[0];
    const float* y_true = (const float*)d_in[1];
    const float* y_pred = (const float*)d_in[2];
    const float* mask = (const float*)d_in[3];
    const int* trip = (const int*)d_in[4];
    const int* valid = (const int*)d_in[5];
    float* out = (float*)d_out;

    int4* ptbl = (int4*)d_ws;                          // 72 * 16 B
    float* partial = (float*)((char*)d_ws + 4096);     // block partials

    const int n = in_sizes[1] / 15;  // N rows (y_true is N x 15)
    const int blocks = (n + 255) / 256;

    pack_tables<<<1, 128, 0, stream>>>(trip, valid, ptbl);
    loss_kernel<<<blocks, 256, 0, stream>>>(x, y_true, y_pred, mask, ptbl, partial, n);
    reduce_kernel<<<1, 256, 0, stream>>>(partial, out, blocks, 1.0f / (float)n);
}